// Round 1
// baseline (1337.900 us; speedup 1.0000x reference)
//
#include <hip/hip_runtime.h>
#include <math.h>

constexpr int MBANK = 128;
constexpr int NSH   = 5;
constexpr int NN    = 8192;          // N
constexpr int DIN   = 512;
constexpr int ODIM  = MBANK + 1 + NSH;   // 134
constexpr int THREADS = 512;
constexpr int NWAVES  = THREADS / 64;    // 8

__global__ __launch_bounds__(THREADS, 1)
void addr_head(const float* __restrict__ input,
               const float* __restrict__ memory,
               const float* __restrict__ prev,
               const float* __restrict__ W,
               const float* __restrict__ bias,
               float* __restrict__ out)
{
    __shared__ __align__(16) float s_scores[NN];     // 32 KB
    __shared__ float s_in[DIN];
    __shared__ __align__(16) float s_args[ODIM + 2];
    __shared__ float s_red[NWAVES];
    __shared__ float s_sd[NSH];
    __shared__ float s_gate, s_max, s_sum;

    const int b    = blockIdx.x;
    const int tid  = threadIdx.x;
    const int lane = tid & 63;
    const int wave = tid >> 6;

    // ---------- stage 1: args = input[b] @ W.T + bias ----------
    for (int d = tid; d < DIN; d += THREADS) s_in[d] = input[(size_t)b * DIN + d];
    __syncthreads();

    for (int o = wave; o < ODIM; o += NWAVES) {
        const float* wrow = W + (size_t)o * DIN;
        float acc = 0.f;
        #pragma unroll
        for (int i = 0; i < DIN / 64; ++i) {
            const int d = lane + i * 64;
            acc += s_in[d] * wrow[d];
        }
        #pragma unroll
        for (int off = 32; off >= 1; off >>= 1) acc += __shfl_xor(acc, off, 64);
        if (lane == 0) s_args[o] = acc + bias[o];
    }
    __syncthreads();

    if (tid == 0) {
        s_gate = 1.0f / (1.0f + expf(-s_args[MBANK]));
        float m = s_args[MBANK + 1];
        #pragma unroll
        for (int s = 1; s < NSH; ++s) m = fmaxf(m, s_args[MBANK + 1 + s]);
        float e[NSH]; float sum = 0.f;
        #pragma unroll
        for (int s = 0; s < NSH; ++s) { e[s] = expf(s_args[MBANK + 1 + s] - m); sum += e[s]; }
        #pragma unroll
        for (int s = 0; s < NSH; ++s) s_sd[s] = e[s] / sum;
    }
    __syncthreads();

    // ---------- stage 2: scores = memory[b] . query / sqrt(128) ----------
    const int pos  = lane & 31;          // which float4 of the 128-wide row
    const int rsub = lane >> 5;          // 0/1: which of the 2 rows this wave-iter
    const float4 q = *(const float4*)&s_args[pos * 4];
    const float4* __restrict__ mem4 = (const float4*)memory + (size_t)b * NN * (MBANK / 4);
    constexpr float SCALE = 0.08838834764831843f;   // 1/sqrt(128)

    const int row0 = wave * 2 + rsub;
    constexpr int RSTEP = NWAVES * 2;    // 16 rows per block-iteration
    #pragma unroll 1
    for (int k = 0; k < NN / RSTEP; k += 4) {
        const int r0 = row0 + (k + 0) * RSTEP;
        const int r1 = row0 + (k + 1) * RSTEP;
        const int r2 = row0 + (k + 2) * RSTEP;
        const int r3 = row0 + (k + 3) * RSTEP;
        float4 v0 = mem4[(size_t)r0 * 32 + pos];
        float4 v1 = mem4[(size_t)r1 * 32 + pos];
        float4 v2 = mem4[(size_t)r2 * 32 + pos];
        float4 v3 = mem4[(size_t)r3 * 32 + pos];
        float d0 = v0.x * q.x + v0.y * q.y + v0.z * q.z + v0.w * q.w;
        float d1 = v1.x * q.x + v1.y * q.y + v1.z * q.z + v1.w * q.w;
        float d2 = v2.x * q.x + v2.y * q.y + v2.z * q.z + v2.w * q.w;
        float d3 = v3.x * q.x + v3.y * q.y + v3.z * q.z + v3.w * q.w;
        #pragma unroll
        for (int off = 16; off >= 1; off >>= 1) {
            d0 += __shfl_xor(d0, off, 32);
            d1 += __shfl_xor(d1, off, 32);
            d2 += __shfl_xor(d2, off, 32);
            d3 += __shfl_xor(d3, off, 32);
        }
        if (pos == 0) {
            s_scores[r0] = d0 * SCALE;
            s_scores[r1] = d1 * SCALE;
            s_scores[r2] = d2 * SCALE;
            s_scores[r3] = d3 * SCALE;
        }
    }
    __syncthreads();

    // ---------- softmax max ----------
    float m = -INFINITY;
    for (int n = tid; n < NN; n += THREADS) m = fmaxf(m, s_scores[n]);
    #pragma unroll
    for (int off = 32; off >= 1; off >>= 1) m = fmaxf(m, __shfl_xor(m, off, 64));
    if (lane == 0) s_red[wave] = m;
    __syncthreads();
    if (tid == 0) {
        float mm = s_red[0];
        for (int w = 1; w < NWAVES; ++w) mm = fmaxf(mm, s_red[w]);
        s_max = mm;
    }
    __syncthreads();

    // ---------- exp + sum ----------
    const float mx = s_max;
    float psum = 0.f;
    for (int n = tid; n < NN; n += THREADS) {
        const float e = expf(s_scores[n] - mx);
        s_scores[n] = e;
        psum += e;
    }
    #pragma unroll
    for (int off = 32; off >= 1; off >>= 1) psum += __shfl_xor(psum, off, 64);
    if (lane == 0) s_red[wave] = psum;
    __syncthreads();
    if (tid == 0) {
        float ss = 0.f;
        for (int w = 0; w < NWAVES; ++w) ss += s_red[w];
        s_sum = ss;
    }
    __syncthreads();

    // ---------- interp = g*content + (1-g)*prev ----------
    const float inv = 1.0f / s_sum;
    const float g   = s_gate;
    const float og  = 1.0f - g;
    const float* __restrict__ prow = prev + (size_t)b * NN;
    for (int n = tid; n < NN; n += THREADS) {
        s_scores[n] = g * (s_scores[n] * inv) + og * prow[n];
    }
    __syncthreads();

    // ---------- circular 5-tap shift conv + store ----------
    const float sd0 = s_sd[0], sd1 = s_sd[1], sd2 = s_sd[2], sd3 = s_sd[3], sd4 = s_sd[4];
    float* __restrict__ orow = out + (size_t)b * NN;
    for (int n = tid; n < NN; n += THREADS) {
        const float r = sd0 * s_scores[(n - 2) & (NN - 1)]
                      + sd1 * s_scores[(n - 1) & (NN - 1)]
                      + sd2 * s_scores[n]
                      + sd3 * s_scores[(n + 1) & (NN - 1)]
                      + sd4 * s_scores[(n + 2) & (NN - 1)];
        orow[n] = r;
    }
}

extern "C" void kernel_launch(void* const* d_in, const int* in_sizes, int n_in,
                              void* d_out, int out_size, void* d_ws, size_t ws_size,
                              hipStream_t stream) {
    const float* input  = (const float*)d_in[0];
    const float* memory = (const float*)d_in[1];
    const float* prev   = (const float*)d_in[2];
    const float* W      = (const float*)d_in[3];
    const float* bias   = (const float*)d_in[4];
    float* out = (float*)d_out;
    const int B = in_sizes[0] / DIN;   // 256
    addr_head<<<B, THREADS, 0, stream>>>(input, memory, prev, W, bias, out);
}